// Round 17
// baseline (4796.627 us; speedup 1.0000x reference)
//
#include <hip/hip_runtime.h>
#include <hip/hip_bf16.h>
#include <hip/hip_fp16.h>
#include <math.h>

#define Q_N 4096
#define M_N 65536
#define D_N 1024
#define TOPK 8
#define SEGS 32
#define KPS (M_N / SEGS)
#define CANDS (SEGS * TOPK)    // fallback path candidates/query
#define NRES 16                // rescored candidates per query

// ---------------- decoupled-path tile params ----------------
#define GBM 256                // keys per block tile
#define GBN 256                // queries per block tile
#define GBK 64
#define GNKT (D_N / GBK)       // 16 K-steps
#define CHUNKQ 1024            // queries per chunk (sims chunk = 128 MB)
#define NCHUNK (Q_N / CHUNKQ)  // 4

// ---------------- fallback (R16) tile params ----------------
#define BM 128
#define BN 128
#define BK 32
#define NSUB (KPS / BN)
#define NKT (D_N / BK)
#define NSTEP (NSUB * NKT)
#define QT128 (Q_N / BM)

typedef short s16x8 __attribute__((ext_vector_type(8)));
typedef float f32x4 __attribute__((ext_vector_type(4)));

__device__ __forceinline__ bool better(float v0, int i0, float v1, int i1) {
  return (v0 > v1) || (v0 == v1 && i0 < i1);
}

__device__ __forceinline__ unsigned short f2bf(float f) {
  union { __hip_bfloat16 h; unsigned short u; } c;
  c.h = __float2bfloat16(f);
  return c.u;
}
__device__ __forceinline__ unsigned short f2h(float f) {
  union { __half h; unsigned short u; } c;
  c.h = __float2half(f);
  return c.u;
}
__device__ __forceinline__ float h2f(unsigned short u) {
  union { __half h; unsigned short u; } c;
  c.u = u;
  return __half2float(c.h);
}

__device__ __forceinline__ void gll16(void* lds, const void* g) {
  __builtin_amdgcn_global_load_lds(
      (const __attribute__((address_space(1))) unsigned int*)(uintptr_t)g,
      (__attribute__((address_space(3))) unsigned int*)(uintptr_t)lds, 16, 0, 0);
}

// ---------------- K1: key norms + normalized bf16 conversion ----------------
__global__ __launch_bounds__(256) void knorm_scale_kernel(const float* __restrict__ keys,
                                                          unsigned short* __restrict__ kb,
                                                          float* __restrict__ rnk) {
  int row = blockIdx.x;
  int tid = threadIdx.x;
  float4 v = reinterpret_cast<const float4*>(keys + (size_t)row * D_N)[tid];
  float s = v.x * v.x + v.y * v.y + v.z * v.z + v.w * v.w;
#pragma unroll
  for (int off = 32; off > 0; off >>= 1) s += __shfl_down(s, off);
  __shared__ float part[4];
  __shared__ float rs;
  int lane = tid & 63, wid = tid >> 6;
  if (lane == 0) part[wid] = s;
  __syncthreads();
  if (tid == 0) {
    float t = part[0] + part[1] + part[2] + part[3];
    rs = 1.0f / fmaxf(sqrtf(t), 1e-12f);
  }
  __syncthreads();
  float r = rs;
  ushort4 o;
  o.x = f2bf(v.x * r); o.y = f2bf(v.y * r); o.z = f2bf(v.z * r); o.w = f2bf(v.w * r);
  reinterpret_cast<ushort4*>(kb + (size_t)row * D_N)[tid] = o;
  if (tid == 0) rnk[row] = r;
}

// ---------------- K2: query norms -> fp32 (rescore) + bf16 (MFMA) ----------
__global__ __launch_bounds__(256) void qnorm_dual_kernel(const float* __restrict__ q,
                                                         float* __restrict__ qn,
                                                         unsigned short* __restrict__ qb) {
  int row = blockIdx.x;
  int tid = threadIdx.x;
  float4 v = reinterpret_cast<const float4*>(q + (size_t)row * D_N)[tid];
  float s = v.x * v.x + v.y * v.y + v.z * v.z + v.w * v.w;
#pragma unroll
  for (int off = 32; off > 0; off >>= 1) s += __shfl_down(s, off);
  __shared__ float part[4];
  __shared__ float rs;
  int lane = tid & 63, wid = tid >> 6;
  if (lane == 0) part[wid] = s;
  __syncthreads();
  if (tid == 0) {
    float t = part[0] + part[1] + part[2] + part[3];
    rs = 1.0f / fmaxf(sqrtf(t), 1e-12f);
  }
  __syncthreads();
  float r = rs;
  float4 o;
  o.x = v.x * r; o.y = v.y * r; o.z = v.z * r; o.w = v.w * r;
  reinterpret_cast<float4*>(qn + (size_t)row * D_N)[tid] = o;
  ushort4 ob;
  ob.x = f2bf(o.x); ob.y = f2bf(o.y); ob.z = f2bf(o.z); ob.w = f2bf(o.w);
  reinterpret_cast<ushort4*>(qb + (size_t)row * D_N)[tid] = ob;
}

// ---------------- GEMM: pure bf16 MFMA sims tile, 256x256, BK=64 ------------
// 8 waves (2k x 4q), wave = 128k x 64q, acc 8x4 f32x4 (128 VGPR, no lists ->
// no spill). 16 fat K-steps: __syncthreads + stage-early double buffer (stage
// t+1 issued right after barrier, consumed next barrier -> full overlap).
// R9 3-bit involutive source swizzle; R5-validated 16x16x32 swapped fragment
// mapping (D[row=key sub][col=query fr]). Epilogue: LDS repack -> coalesced
// f16 sims[queryLocal][key] writes.
__global__ __launch_bounds__(512, 2) void gemm_kernel(const unsigned short* __restrict__ qb,
                                                      const unsigned short* __restrict__ kb,
                                                      unsigned short* __restrict__ sims,
                                                      int qchunk) {
  __shared__ __align__(16) union GSmem {
    struct {
      unsigned short A[2][GBN * GBK];  // 2 x 32 KB queries
      unsigned short B[2][GBM * GBK];  // 2 x 32 KB keys
    } ab;                              // 128 KB
    unsigned short S[GBN][GBM + 8];    // 256 x 264 f16 = 132 KB (pad: banks)
  } smem;

  const int tid = threadIdx.x;
  const int lane = tid & 63;
  const int wid = tid >> 6;        // 0..7
  const int wq = wid & 3;          // query quarter (64 q)
  const int wk = wid >> 2;         // key half (128 k)

  // mapping: x = XCD, idx in-XCD (0..127); 8 key-tiles x 4 q-tiles co-round
  const int bid = blockIdx.x;
  const int x = bid & 7;
  const int idx = bid >> 3;
  const int keyTile = (x << 5) + (idx >> 2);   // 0..255
  const int qTile = idx & 3;
  const int kbase = keyTile * GBM;
  const int qbase = qchunk * CHUNKQ + qTile * GBN;  // global query row
  const int qloc0 = qTile * GBN;                    // within-chunk row

  // staging: wave wid stages A rows [wid*32,+32) and B rows [wid*32,+32),
  // 4 gll16 each (8 rows per gll16). Source pre-swizzled, LDS linear.
  const int srow8 = lane >> 3;
  const int swz = ((lane & 7) ^ srow8) << 3;
  const unsigned short* aRow = qb + (size_t)(qbase + (wid << 5) + srow8) * D_N + swz;
  const unsigned short* bRow = kb + (size_t)(kbase + (wid << 5) + srow8) * D_N + swz;

  // fragment geometry: logical chunk c = kh*4+g lives at phys c ^ (row&7)
  const int fr = lane & 15;
  const int g = lane >> 4;
  const int ph0 = ((0 + g) ^ (fr & 7)) << 3;   // kh=0
  const int ph1 = ((4 + g) ^ (fr & 7)) << 3;   // kh=1

  f32x4 acc[8][4];
#pragma unroll
  for (int m = 0; m < 8; ++m)
#pragma unroll
    for (int n = 0; n < 4; ++n) acc[m][n] = (f32x4)0.0f;

  // prologue: stage step 0 -> buf 0
#pragma unroll
  for (int i = 0; i < 4; ++i) {
    gll16(&smem.ab.A[0][0] + (wid << 11) + (i << 9), aRow + (size_t)(i << 3) * D_N);
    gll16(&smem.ab.B[0][0] + (wid << 11) + (i << 9), bRow + (size_t)(i << 3) * D_N);
  }

#pragma unroll 1
  for (int t = 0; t < GNKT; ++t) {
    __syncthreads();   // drains stage(t); all reads of buf[(t+1)&1] (step t-1) done
    if (t + 1 < GNKT) {
      const int k2 = (t + 1) << 6;   // ush k-offset
#pragma unroll
      for (int i = 0; i < 4; ++i) {
        gll16(&smem.ab.A[(t + 1) & 1][0] + (wid << 11) + (i << 9),
              aRow + k2 + (size_t)(i << 3) * D_N);
        gll16(&smem.ab.B[(t + 1) & 1][0] + (wid << 11) + (i << 9),
              bRow + k2 + (size_t)(i << 3) * D_N);
      }
    }
    const unsigned short* Ab = &smem.ab.A[t & 1][0];
    const unsigned short* Bb = &smem.ab.B[t & 1][0];
    // kh = 0
    {
      s16x8 bq[4], af[8];
#pragma unroll
      for (int n = 0; n < 4; ++n)
        bq[n] = *(const s16x8*)(Ab + ((wq << 6) + (n << 4) + fr) * GBK + ph0);
#pragma unroll
      for (int m = 0; m < 8; ++m)
        af[m] = *(const s16x8*)(Bb + ((wk << 7) + (m << 4) + fr) * GBK + ph0);
      __builtin_amdgcn_s_setprio(1);
#pragma unroll
      for (int m = 0; m < 8; ++m)
#pragma unroll
        for (int n = 0; n < 4; ++n)
          acc[m][n] = __builtin_amdgcn_mfma_f32_16x16x32_bf16(af[m], bq[n], acc[m][n], 0, 0, 0);
      __builtin_amdgcn_s_setprio(0);
    }
    // kh = 1
    {
      s16x8 bq[4], af[8];
#pragma unroll
      for (int n = 0; n < 4; ++n)
        bq[n] = *(const s16x8*)(Ab + ((wq << 6) + (n << 4) + fr) * GBK + ph1);
#pragma unroll
      for (int m = 0; m < 8; ++m)
        af[m] = *(const s16x8*)(Bb + ((wk << 7) + (m << 4) + fr) * GBK + ph1);
      __builtin_amdgcn_s_setprio(1);
#pragma unroll
      for (int m = 0; m < 8; ++m)
#pragma unroll
        for (int n = 0; n < 4; ++n)
          acc[m][n] = __builtin_amdgcn_mfma_f32_16x16x32_bf16(af[m], bq[n], acc[m][n], 0, 0, 0);
      __builtin_amdgcn_s_setprio(0);
    }
  }

  __syncthreads();   // ab dead; reuse as S
  // D map (R5-validated): row-within-16 = g*4+j (KEY), col = fr (QUERY)
#pragma unroll
  for (int m = 0; m < 8; ++m)
#pragma unroll
    for (int n = 0; n < 4; ++n)
#pragma unroll
      for (int j = 0; j < 4; ++j)
        smem.S[(wq << 6) + (n << 4) + fr][(wk << 7) + (m << 4) + (g << 2) + j] =
            f2h(acc[m][n][j]);
  __syncthreads();
  // coalesced dump: 8192 chunks of 16 B
#pragma unroll 1
  for (int it = 0; it < 16; ++it) {
    int cid = it * 512 + tid;
    int row = cid >> 5;
    int col = (cid & 31) << 3;
    s16x8 vv = *(const s16x8*)&smem.S[row][col];
    *(s16x8*)(sims + (size_t)(qloc0 + row) * M_N + kbase + col) = vv;
  }
}

// ---------------- SCAN: exact f16 top-16 per query row ----------------------
// block = one query row; per-thread exact top-16 of its strided 256-value
// partition; merge-truncate-16 tree (exact: union top-16 subset of children
// top-16s). Output sorted 16 candidates per query.
__global__ __launch_bounds__(256) void scan_kernel(const unsigned short* __restrict__ sims,
                                                   float* __restrict__ cand_val,
                                                   int* __restrict__ cand_idx,
                                                   int qchunk) {
  __shared__ float mv[256 * 16];
  __shared__ int mi[256 * 16];
  const int tid = threadIdx.x;
  const int q = blockIdx.x;   // 0..CHUNKQ-1
  const unsigned short* row = sims + (size_t)q * M_N;

  float lv[16];
  int li[16];
#pragma unroll
  for (int j = 0; j < 16; ++j) { lv[j] = -1e30f; li[j] = 0x7fffffff; }

#pragma unroll 1
  for (int it = 0; it < 32; ++it) {
    const int base = (it << 11) + (tid << 3);
    s16x8 pk = *(const s16x8*)(row + base);
#pragma unroll
    for (int j = 0; j < 8; ++j) {
      float v = h2f((unsigned short)pk[j]);
      int id = base + j;
      if (better(v, id, lv[15], li[15])) {
        float cv = v; int ci = id;
#pragma unroll
        for (int p = 0; p < 16; ++p) {
          if (better(cv, ci, lv[p], li[p])) {
            float tv = lv[p]; int ti = li[p];
            lv[p] = cv; li[p] = ci;
            cv = tv; ci = ti;
          }
        }
      }
    }
  }
#pragma unroll
  for (int j = 0; j < 16; ++j) { mv[tid * 16 + j] = lv[j]; mi[tid * 16 + j] = li[j]; }

  for (int s = 128; s >= 1; s >>= 1) {
    __syncthreads();
    if (tid < s) {
      const int a = tid * 16, b = (tid + s) * 16;
      float ov[16]; int oi[16];
      int pa = 0, pb = 0;
#pragma unroll
      for (int j = 0; j < 16; ++j) {
        float va = (pa < 16) ? mv[a + pa] : -1e38f;
        int ia = (pa < 16) ? mi[a + pa] : 0x7fffffff;
        float vb = (pb < 16) ? mv[b + pb] : -1e38f;
        int ib = (pb < 16) ? mi[b + pb] : 0x7fffffff;
        bool ta = better(va, ia, vb, ib);
        ov[j] = ta ? va : vb;
        oi[j] = ta ? ia : ib;
        pa += ta ? 1 : 0;
        pb += ta ? 0 : 1;
      }
#pragma unroll
      for (int j = 0; j < 16; ++j) { mv[a + j] = ov[j]; mi[a + j] = oi[j]; }
    }
  }
  __syncthreads();
  if (tid < 16) {
    const int qg = qchunk * CHUNKQ + q;
    cand_val[(size_t)qg * 16 + tid] = mv[tid];
    cand_idx[(size_t)qg * 16 + tid] = mi[tid];
  }
}

// ---------------- RESCORE: exact fp32 rescore of 16 + select + gather -------
__global__ __launch_bounds__(256) void rescore_kernel(const float* __restrict__ qn,
                                                      const float* __restrict__ keys,
                                                      const float* __restrict__ values,
                                                      const float* __restrict__ rnk,
                                                      const int* __restrict__ cand_idx,
                                                      float* __restrict__ out) {
  const int q = blockIdx.x;
  const int tid = threadIdx.x;
  const int lane = tid & 63;
  const int w = tid >> 6;
  __shared__ int si[16];
  __shared__ float rsc[16];
  if (tid < 16) si[tid] = cand_idx[(size_t)q * 16 + tid];
  __syncthreads();
  const float* qrow = &qn[(size_t)q * D_N + lane * 16];
  float4 qv0 = *reinterpret_cast<const float4*>(qrow + 0);
  float4 qv1 = *reinterpret_cast<const float4*>(qrow + 4);
  float4 qv2 = *reinterpret_cast<const float4*>(qrow + 8);
  float4 qv3 = *reinterpret_cast<const float4*>(qrow + 12);
  for (int c = w; c < 16; c += 4) {
    int id = si[c];
    const float* kr = &keys[(size_t)id * D_N + lane * 16];
    float4 k0 = *reinterpret_cast<const float4*>(kr + 0);
    float4 k1 = *reinterpret_cast<const float4*>(kr + 4);
    float4 k2 = *reinterpret_cast<const float4*>(kr + 8);
    float4 k3 = *reinterpret_cast<const float4*>(kr + 12);
    float s = qv0.x * k0.x + qv0.y * k0.y + qv0.z * k0.z + qv0.w * k0.w
            + qv1.x * k1.x + qv1.y * k1.y + qv1.z * k1.z + qv1.w * k1.w
            + qv2.x * k2.x + qv2.y * k2.y + qv2.z * k2.z + qv2.w * k2.w
            + qv3.x * k3.x + qv3.y * k3.y + qv3.z * k3.z + qv3.w * k3.w;
#pragma unroll
    for (int off = 32; off > 0; off >>= 1) s += __shfl_down(s, off);
    if (lane == 0) rsc[c] = s * rnk[id];
  }
  __syncthreads();
  __shared__ int sel[TOPK];
  if (tid == 0) {
    unsigned used = 0;
    for (int j = 0; j < TOPK; ++j) {
      int best = -1;
      for (int c = 0; c < 16; ++c) {
        if ((used >> c) & 1u) continue;
        if (best < 0 || better(rsc[c], si[c], rsc[best], si[best])) best = c;
      }
      used |= 1u << best;
      sel[j] = si[best];
    }
  }
  __syncthreads();
#pragma unroll
  for (int j = 0; j < TOPK; ++j) {
    int rowi = sel[j];
    float4 v = *reinterpret_cast<const float4*>(&values[(size_t)rowi * D_N + tid * 4]);
    *reinterpret_cast<float4*>(&out[(size_t)q * (TOPK * D_N) + j * D_N + tid * 4]) = v;
  }
}

// =================== FALLBACK (R16, validated) ==============================
__global__ __launch_bounds__(256, 3) void simsb_kernel(const unsigned short* __restrict__ qb,
                                                       const unsigned short* __restrict__ kb,
                                                       float* __restrict__ cand_val,
                                                       int* __restrict__ cand_idx) {
  __shared__ __align__(16) union SmemU {
    struct {
      unsigned short A[3][BM * BK];
      unsigned short B[3][BN * BK];
    } ab;
    struct {
      float v[BM * 4 * TOPK];
      int i[BM * 4 * TOPK];
    } mg;
  } smem;

  const int tid = threadIdx.x;
  const int lane = tid & 63;
  const int wid = tid >> 6;

  const int orig = blockIdx.x;
  const int x = orig & 7;
  const int idx = orig >> 3;
  const int qtile = ((x >> 1) << 3) + (idx & 7);
  const int seg = ((x & 1) << 4) + (idx >> 3);
  const int qbase = qtile * BM;
  const int segBase = seg * KPS;

  const int srow = (wid << 5) + (lane >> 2);
  const int scol = (((lane & 3) ^ ((lane >> 3) & 3)) << 3);
  const unsigned short* aSeg = qb + (size_t)(qbase + srow) * D_N + scol;
  const unsigned short* bSeg = kb + (size_t)(segBase + srow) * D_N + scol;

  const int fr = lane & 15;
  const int g = lane >> 4;
  const int chunk_phys = g ^ ((fr >> 1) & 3);
  const unsigned short* rB = &smem.ab.B[0][0] + (fr << 5) + (chunk_phys << 3);
  const unsigned short* rA = &smem.ab.A[0][0] + (((wid << 5) + fr) << 5) + (chunk_phys << 3);

  float lv[2][TOPK];
  int li[2][TOPK];
#pragma unroll
  for (int n = 0; n < 2; ++n)
#pragma unroll
    for (int j = 0; j < TOPK; ++j) { lv[n][j] = -1e30f; li[n][j] = 0x7fffffff; }

  f32x4 acc[8][2];
#pragma unroll
  for (int m = 0; m < 8; ++m)
#pragma unroll
    for (int n = 0; n < 2; ++n) acc[m][n] = (f32x4)0.0f;

#pragma unroll
  for (int p = 0; p < 2; ++p) {
    const unsigned short* aS = aSeg + (p << 5);
    const unsigned short* bS = bSeg + (p << 5);
    unsigned short* Ad = &smem.ab.A[p][0] + (wid << 10);
    unsigned short* Bd = &smem.ab.B[p][0] + (wid << 10);
    gll16(Ad, aS);
    gll16(Ad + 512, aS + (size_t)16 * D_N);
    gll16(Bd, bS);
    gll16(Bd + 512, bS + (size_t)16 * D_N);
  }

  const unsigned short* aP0 = aSeg + 64;
  const unsigned short* aP1 = aP0 + (size_t)16 * D_N;
  const unsigned short* bP0 = bSeg + 64;
  const unsigned short* bP1 = bP0 + (size_t)16 * D_N;

#define SWAIT_(N) asm volatile("s_waitcnt vmcnt(" #N ")" ::: "memory")
#define SWAIT(N) SWAIT_(N)

#define FOLD(V)                                                               \
  {                                                                           \
    const int kb0 = segBase + (((V) >> 5) << 7) + (g << 2);                   \
    _Pragma("unroll")                                                         \
    for (int n = 0; n < 2; ++n)                                               \
      _Pragma("unroll")                                                       \
      for (int m = 0; m < 8; ++m) {                                           \
        float q0 = acc[m][n][0], q1 = acc[m][n][1];                           \
        float q2 = acc[m][n][2], q3 = acc[m][n][3];                           \
        acc[m][n] = (f32x4)0.0f;                                              \
        float mx = fmaxf(fmaxf(q0, q1), fmaxf(q2, q3));                       \
        const int id0 = kb0 + (m << 4);                                       \
        if (better(mx, id0, lv[n][TOPK - 1], li[n][TOPK - 1])) {              \
          float vals[4] = {q0, q1, q2, q3};                                   \
          _Pragma("unroll")                                                   \
          for (int j = 0; j < 4; ++j) {                                       \
            float val = vals[j];                                              \
            int id = id0 + j;                                                 \
            if (better(val, id, lv[n][TOPK - 1], li[n][TOPK - 1])) {          \
              float cv = val; int ci = id;                                    \
              _Pragma("unroll")                                               \
              for (int p = 0; p < TOPK; ++p) {                                \
                if (better(cv, ci, lv[n][p], li[n][p])) {                     \
                  float tv = lv[n][p]; int ti = li[n][p];                     \
                  lv[n][p] = cv; li[n][p] = ci;                               \
                  cv = tv; ci = ti;                                           \
                }                                                             \
              }                                                               \
            }                                                                 \
          }                                                                   \
        }                                                                     \
      }                                                                       \
  }

#define STEP(V, SLOT, WAITN, RESTAGE)                                         \
  {                                                                           \
    SWAIT(WAITN);                                                             \
    __builtin_amdgcn_sched_barrier(0);                                        \
    __builtin_amdgcn_s_barrier();                                             \
    __builtin_amdgcn_sched_barrier(0);                                        \
    if (RESTAGE) {                                                            \
      unsigned short* Ad = &smem.ab.A[((SLOT) + 2) % 3][0] + (wid << 10);     \
      unsigned short* Bd = &smem.ab.B[((SLOT) + 2) % 3][0] + (wid << 10);     \
      gll16(Ad, aP0);                                                         \
      gll16(Ad + 512, aP1);                                                   \
      gll16(Bd, bP0);                                                         \
      gll16(Bd + 512, bP1);                                                   \
    }                                                                         \
    {                                                                         \
      const bool wrp = (((V) & 31) == 29);                                    \
      const int dA = wrp ? -992 : 32;                                         \
      const int dB = wrp ? 130080 : 32;                                       \
      aP0 += dA; aP1 += dA; bP0 += dB; bP1 += dB;                             \
    }                                                                         \
    s16x8 af[8], bq[2];                                                       \
    _Pragma("unroll")                                                         \
    for (int m = 0; m < 8; ++m)                                               \
      af[m] = *(const s16x8*)(rB + (SLOT) * 4096 + (m << 9));                 \
    bq[0] = *(const s16x8*)(rA + (SLOT) * 4096);                              \
    bq[1] = *(const s16x8*)(rA + (SLOT) * 4096 + 512);                        \
    __builtin_amdgcn_s_setprio(1);                                            \
    _Pragma("unroll")                                                         \
    for (int m = 0; m < 8; ++m) {                                             \
      acc[m][0] = __builtin_amdgcn_mfma_f32_16x16x32_bf16(af[m], bq[0], acc[m][0], 0, 0, 0); \
      acc[m][1] = __builtin_amdgcn_mfma_f32_16x16x32_bf16(af[m], bq[1], acc[m][1], 0, 0, 0); \
    }                                                                         \
    __builtin_amdgcn_s_setprio(0);                                            \
    if (((V) & 31) == 31) FOLD(V)                                             \
  }

#pragma unroll 1
  for (int vb = 0; vb < NSTEP - 2; vb += 3) {
    STEP(vb + 0, 0, 4, 1)
    STEP(vb + 1, 1, 4, 1)
    STEP(vb + 2, 2, 4, 1)
  }
  STEP(510, 0, 4, 0)
  STEP(511, 1, 0, 0)
#undef STEP
#undef FOLD
#undef SWAIT
#undef SWAIT_

  __syncthreads();

#pragma unroll
  for (int n = 0; n < 2; ++n) {
    const int ql = (wid << 5) + (n << 4) + fr;
#pragma unroll
    for (int j = 0; j < TOPK; ++j) {
      smem.mg.v[((ql << 2) + g) * TOPK + j] = lv[n][j];
      smem.mg.i[((ql << 2) + g) * TOPK + j] = li[n][j];
    }
  }
  __syncthreads();

  if (tid < BM) {
    const int rb = tid << 5;
    int p0 = 0, p1 = 0, p2 = 0, p3 = 0;
    size_t base = (size_t)(qbase + tid) * CANDS + seg * TOPK;
#pragma unroll
    for (int j = 0; j < TOPK; ++j) {
      float v0 = smem.mg.v[rb + 0 + p0];  int i0 = smem.mg.i[rb + 0 + p0];
      float v1 = smem.mg.v[rb + 8 + p1];  int i1 = smem.mg.i[rb + 8 + p1];
      float v2 = smem.mg.v[rb + 16 + p2]; int i2 = smem.mg.i[rb + 16 + p2];
      float v3 = smem.mg.v[rb + 24 + p3]; int i3 = smem.mg.i[rb + 24 + p3];
      float bv = v0; int bi = i0; int sel = 0;
      if (better(v1, i1, bv, bi)) { bv = v1; bi = i1; sel = 1; }
      if (better(v2, i2, bv, bi)) { bv = v2; bi = i2; sel = 2; }
      if (better(v3, i3, bv, bi)) { bv = v3; bi = i3; sel = 3; }
      cand_val[base + j] = bv;
      cand_idx[base + j] = bi;
      p0 += (sel == 0); p1 += (sel == 1); p2 += (sel == 2); p3 += (sel == 3);
    }
  }
}

__global__ __launch_bounds__(256) void merge_kernel(const float* __restrict__ qn,
                                                    const float* __restrict__ keys,
                                                    const float* __restrict__ values,
                                                    const float* __restrict__ rnk,
                                                    const float* __restrict__ cand_val,
                                                    const int* __restrict__ cand_idx,
                                                    float* __restrict__ out) {
  const int q = blockIdx.x;
  const int tid = threadIdx.x;
  const int lane = tid & 63;
  const int w = tid >> 6;
  __shared__ float sv[CANDS];
  __shared__ int si[CANDS];
  sv[tid] = cand_val[(size_t)q * CANDS + tid];
  si[tid] = cand_idx[(size_t)q * CANDS + tid];
  __syncthreads();
  for (int k = 2; k <= CANDS; k <<= 1) {
    for (int j = k >> 1; j > 0; j >>= 1) {
      int ixj = tid ^ j;
      if (ixj > tid) {
        float v0 = sv[tid], v1 = sv[ixj];
        int i0 = si[tid], i1 = si[ixj];
        bool desc = ((tid & k) == 0);
        bool dosw = desc ? better(v1, i1, v0, i0) : better(v0, i0, v1, i1);
        if (dosw) { sv[tid] = v1; si[tid] = i1; sv[ixj] = v0; si[ixj] = i0; }
      }
      __syncthreads();
    }
  }
  __shared__ float rsc[NRES];
  const float* qrow = &qn[(size_t)q * D_N + lane * 16];
  float4 qv0 = *reinterpret_cast<const float4*>(qrow + 0);
  float4 qv1 = *reinterpret_cast<const float4*>(qrow + 4);
  float4 qv2 = *reinterpret_cast<const float4*>(qrow + 8);
  float4 qv3 = *reinterpret_cast<const float4*>(qrow + 12);
  for (int c = w; c < NRES; c += 4) {
    int id = si[c];
    const float* kr = &keys[(size_t)id * D_N + lane * 16];
    float4 k0 = *reinterpret_cast<const float4*>(kr + 0);
    float4 k1 = *reinterpret_cast<const float4*>(kr + 4);
    float4 k2 = *reinterpret_cast<const float4*>(kr + 8);
    float4 k3 = *reinterpret_cast<const float4*>(kr + 12);
    float s = qv0.x * k0.x + qv0.y * k0.y + qv0.z * k0.z + qv0.w * k0.w
            + qv1.x * k1.x + qv1.y * k1.y + qv1.z * k1.z + qv1.w * k1.w
            + qv2.x * k2.x + qv2.y * k2.y + qv2.z * k2.z + qv2.w * k2.w
            + qv3.x * k3.x + qv3.y * k3.y + qv3.z * k3.z + qv3.w * k3.w;
#pragma unroll
    for (int off = 32; off > 0; off >>= 1) s += __shfl_down(s, off);
    if (lane == 0) rsc[c] = s * rnk[id];
  }
  __syncthreads();
  __shared__ int sel[TOPK];
  if (tid == 0) {
    unsigned used = 0;
    for (int j = 0; j < TOPK; ++j) {
      int best = -1;
      for (int c = 0; c < NRES; ++c) {
        if ((used >> c) & 1u) continue;
        if (best < 0 || better(rsc[c], si[c], rsc[best], si[best])) best = c;
      }
      used |= 1u << best;
      sel[j] = si[best];
    }
  }
  __syncthreads();
#pragma unroll
  for (int j = 0; j < TOPK; ++j) {
    int row = sel[j];
    float4 v = *reinterpret_cast<const float4*>(&values[(size_t)row * D_N + tid * 4]);
    *reinterpret_cast<float4*>(&out[(size_t)q * (TOPK * D_N) + j * D_N + tid * 4]) = v;
  }
}

extern "C" void kernel_launch(void* const* d_in, const int* in_sizes, int n_in,
                              void* d_out, int out_size, void* d_ws, size_t ws_size,
                              hipStream_t stream) {
  const float* query  = (const float*)d_in[0];
  const float* keys   = (const float*)d_in[1];
  const float* values = (const float*)d_in[2];
  float* out = (float*)d_out;
  char* ws = (char*)d_ws;

  const size_t offQn   = 0;
  const size_t offQb   = offQn + (size_t)Q_N * D_N * 4;          // 16 MB
  const size_t offKb   = offQb + (size_t)Q_N * D_N * 2;          // + 8 MB
  const size_t offRnk  = offKb + (size_t)M_N * D_N * 2;          // + 128 MB
  const size_t offCv   = offRnk + (size_t)M_N * 4;               // + 0.25 MB
  const size_t offCi   = offCv + (size_t)Q_N * CANDS * 4;        // + 4 MB
  const size_t offSims = offCi + (size_t)Q_N * CANDS * 4;        // + 4 MB
  const size_t needPrimary = offSims + (size_t)CHUNKQ * M_N * 2; // + 128 MB

  float* qn = (float*)(ws + offQn);
  unsigned short* qb = (unsigned short*)(ws + offQb);
  unsigned short* kb = (unsigned short*)(ws + offKb);
  float* rnk = (float*)(ws + offRnk);
  float* cand_val = (float*)(ws + offCv);
  int* cand_idx = (int*)(ws + offCi);
  unsigned short* sims = (unsigned short*)(ws + offSims);

  hipLaunchKernelGGL(knorm_scale_kernel, dim3(M_N), dim3(256), 0, stream, keys, kb, rnk);
  hipLaunchKernelGGL(qnorm_dual_kernel, dim3(Q_N), dim3(256), 0, stream, query, qn, qb);

  if (ws_size >= needPrimary) {
    for (int c = 0; c < NCHUNK; ++c) {
      hipLaunchKernelGGL(gemm_kernel, dim3(256 * 4), dim3(512), 0, stream, qb, kb, sims, c);
      hipLaunchKernelGGL(scan_kernel, dim3(CHUNKQ), dim3(256), 0, stream,
                         sims, cand_val, cand_idx, c);
    }
    hipLaunchKernelGGL(rescore_kernel, dim3(Q_N), dim3(256), 0, stream,
                       qn, keys, values, rnk, cand_idx, out);
  } else {
    hipLaunchKernelGGL(simsb_kernel, dim3(QT128 * SEGS), dim3(256), 0, stream,
                       qb, kb, cand_val, cand_idx);
    hipLaunchKernelGGL(merge_kernel, dim3(Q_N), dim3(256), 0, stream,
                       qn, keys, values, rnk, cand_val, cand_idx, out);
  }
}

// Round 18
// 857.678 us; speedup vs baseline: 5.5926x; 5.5926x over previous
//
#include <hip/hip_runtime.h>
#include <hip/hip_bf16.h>
#include <hip/hip_fp16.h>
#include <math.h>

#define Q_N 4096
#define M_N 65536
#define D_N 1024
#define TOPK 8
#define SEGS 32
#define KPS (M_N / SEGS)
#define CANDS (SEGS * TOPK)    // fallback path candidates/query
#define NRES 16                // fallback rescored candidates per query

// ---------------- decoupled-path tile params ----------------
#define GBM 256                // keys per block tile
#define GBN 256                // queries per block tile
#define GBK 64
#define GNKT (D_N / GBK)       // 16 K-steps
#define CHUNKQ 1024            // queries per chunk (sims chunk = 128 MB)
#define NCHUNK (Q_N / CHUNKQ)  // 4
#define NTILES (M_N / GBM)     // 256 key tiles
#define CAP 512                // scan candidate buffer per row

// ---------------- fallback (R16) tile params ----------------
#define BM 128
#define BN 128
#define BK 32
#define NSUB (KPS / BN)
#define NKT (D_N / BK)
#define NSTEP (NSUB * NKT)
#define QT128 (Q_N / BM)

typedef short s16x8 __attribute__((ext_vector_type(8)));
typedef float f32x4 __attribute__((ext_vector_type(4)));

__device__ __forceinline__ bool better(float v0, int i0, float v1, int i1) {
  return (v0 > v1) || (v0 == v1 && i0 < i1);
}

__device__ __forceinline__ unsigned short f2bf(float f) {
  union { __hip_bfloat16 h; unsigned short u; } c;
  c.h = __float2bfloat16(f);
  return c.u;
}
__device__ __forceinline__ unsigned short f2h(float f) {
  union { __half h; unsigned short u; } c;
  c.h = __float2half(f);
  return c.u;
}
__device__ __forceinline__ float h2f(unsigned short u) {
  union { __half h; unsigned short u; } c;
  c.u = u;
  return __half2float(c.h);
}

__device__ __forceinline__ void gll16(void* lds, const void* g) {
  __builtin_amdgcn_global_load_lds(
      (const __attribute__((address_space(1))) unsigned int*)(uintptr_t)g,
      (__attribute__((address_space(3))) unsigned int*)(uintptr_t)lds, 16, 0, 0);
}

// ---------------- K1: key norms + normalized bf16 conversion ----------------
__global__ __launch_bounds__(256) void knorm_scale_kernel(const float* __restrict__ keys,
                                                          unsigned short* __restrict__ kb,
                                                          float* __restrict__ rnk) {
  int row = blockIdx.x;
  int tid = threadIdx.x;
  float4 v = reinterpret_cast<const float4*>(keys + (size_t)row * D_N)[tid];
  float s = v.x * v.x + v.y * v.y + v.z * v.z + v.w * v.w;
#pragma unroll
  for (int off = 32; off > 0; off >>= 1) s += __shfl_down(s, off);
  __shared__ float part[4];
  __shared__ float rs;
  int lane = tid & 63, wid = tid >> 6;
  if (lane == 0) part[wid] = s;
  __syncthreads();
  if (tid == 0) {
    float t = part[0] + part[1] + part[2] + part[3];
    rs = 1.0f / fmaxf(sqrtf(t), 1e-12f);
  }
  __syncthreads();
  float r = rs;
  ushort4 o;
  o.x = f2bf(v.x * r); o.y = f2bf(v.y * r); o.z = f2bf(v.z * r); o.w = f2bf(v.w * r);
  reinterpret_cast<ushort4*>(kb + (size_t)row * D_N)[tid] = o;
  if (tid == 0) rnk[row] = r;
}

// ---------------- K2: query norms -> fp32 (rescore) + bf16 (MFMA) ----------
__global__ __launch_bounds__(256) void qnorm_dual_kernel(const float* __restrict__ q,
                                                         float* __restrict__ qn,
                                                         unsigned short* __restrict__ qb) {
  int row = blockIdx.x;
  int tid = threadIdx.x;
  float4 v = reinterpret_cast<const float4*>(q + (size_t)row * D_N)[tid];
  float s = v.x * v.x + v.y * v.y + v.z * v.z + v.w * v.w;
#pragma unroll
  for (int off = 32; off > 0; off >>= 1) s += __shfl_down(s, off);
  __shared__ float part[4];
  __shared__ float rs;
  int lane = tid & 63, wid = tid >> 6;
  if (lane == 0) part[wid] = s;
  __syncthreads();
  if (tid == 0) {
    float t = part[0] + part[1] + part[2] + part[3];
    rs = 1.0f / fmaxf(sqrtf(t), 1e-12f);
  }
  __syncthreads();
  float r = rs;
  float4 o;
  o.x = v.x * r; o.y = v.y * r; o.z = v.z * r; o.w = v.w * r;
  reinterpret_cast<float4*>(qn + (size_t)row * D_N)[tid] = o;
  ushort4 ob;
  ob.x = f2bf(o.x); ob.y = f2bf(o.y); ob.z = f2bf(o.z); ob.w = f2bf(o.w);
  reinterpret_cast<ushort4*>(qb + (size_t)row * D_N)[tid] = ob;
}

// ---------------- GEMM: pure bf16 MFMA sims tile, 256x256, BK=64 ------------
// R17-validated (~90 us/chunk). Added epilogue: per-row 256-key tile max
// (computed from the STORED f16 values in the S tile -> threshold-consistent)
// written to qmax[CHUNKQ][NTILES].
__global__ __launch_bounds__(512, 2) void gemm_kernel(const unsigned short* __restrict__ qb,
                                                      const unsigned short* __restrict__ kb,
                                                      unsigned short* __restrict__ sims,
                                                      float* __restrict__ qmax,
                                                      int qchunk) {
  __shared__ __align__(16) union GSmem {
    struct {
      unsigned short A[2][GBN * GBK];  // 2 x 32 KB queries
      unsigned short B[2][GBM * GBK];  // 2 x 32 KB keys
    } ab;                              // 128 KB
    unsigned short S[GBN][GBM + 8];    // 256 x 264 f16 = 132 KB
  } smem;

  const int tid = threadIdx.x;
  const int lane = tid & 63;
  const int wid = tid >> 6;
  const int wq = wid & 3;
  const int wk = wid >> 2;

  const int bid = blockIdx.x;
  const int x = bid & 7;
  const int idx = bid >> 3;
  const int keyTile = (x << 5) + (idx >> 2);
  const int qTile = idx & 3;
  const int kbase = keyTile * GBM;
  const int qbase = qchunk * CHUNKQ + qTile * GBN;
  const int qloc0 = qTile * GBN;

  const int srow8 = lane >> 3;
  const int swz = ((lane & 7) ^ srow8) << 3;
  const unsigned short* aRow = qb + (size_t)(qbase + (wid << 5) + srow8) * D_N + swz;
  const unsigned short* bRow = kb + (size_t)(kbase + (wid << 5) + srow8) * D_N + swz;

  const int fr = lane & 15;
  const int g = lane >> 4;
  const int ph0 = ((0 + g) ^ (fr & 7)) << 3;
  const int ph1 = ((4 + g) ^ (fr & 7)) << 3;

  f32x4 acc[8][4];
#pragma unroll
  for (int m = 0; m < 8; ++m)
#pragma unroll
    for (int n = 0; n < 4; ++n) acc[m][n] = (f32x4)0.0f;

#pragma unroll
  for (int i = 0; i < 4; ++i) {
    gll16(&smem.ab.A[0][0] + (wid << 11) + (i << 9), aRow + (size_t)(i << 3) * D_N);
    gll16(&smem.ab.B[0][0] + (wid << 11) + (i << 9), bRow + (size_t)(i << 3) * D_N);
  }

#pragma unroll 1
  for (int t = 0; t < GNKT; ++t) {
    __syncthreads();
    if (t + 1 < GNKT) {
      const int k2 = (t + 1) << 6;
#pragma unroll
      for (int i = 0; i < 4; ++i) {
        gll16(&smem.ab.A[(t + 1) & 1][0] + (wid << 11) + (i << 9),
              aRow + k2 + (size_t)(i << 3) * D_N);
        gll16(&smem.ab.B[(t + 1) & 1][0] + (wid << 11) + (i << 9),
              bRow + k2 + (size_t)(i << 3) * D_N);
      }
    }
    const unsigned short* Ab = &smem.ab.A[t & 1][0];
    const unsigned short* Bb = &smem.ab.B[t & 1][0];
    {
      s16x8 bq[4], af[8];
#pragma unroll
      for (int n = 0; n < 4; ++n)
        bq[n] = *(const s16x8*)(Ab + ((wq << 6) + (n << 4) + fr) * GBK + ph0);
#pragma unroll
      for (int m = 0; m < 8; ++m)
        af[m] = *(const s16x8*)(Bb + ((wk << 7) + (m << 4) + fr) * GBK + ph0);
      __builtin_amdgcn_s_setprio(1);
#pragma unroll
      for (int m = 0; m < 8; ++m)
#pragma unroll
        for (int n = 0; n < 4; ++n)
          acc[m][n] = __builtin_amdgcn_mfma_f32_16x16x32_bf16(af[m], bq[n], acc[m][n], 0, 0, 0);
      __builtin_amdgcn_s_setprio(0);
    }
    {
      s16x8 bq[4], af[8];
#pragma unroll
      for (int n = 0; n < 4; ++n)
        bq[n] = *(const s16x8*)(Ab + ((wq << 6) + (n << 4) + fr) * GBK + ph1);
#pragma unroll
      for (int m = 0; m < 8; ++m)
        af[m] = *(const s16x8*)(Bb + ((wk << 7) + (m << 4) + fr) * GBK + ph1);
      __builtin_amdgcn_s_setprio(1);
#pragma unroll
      for (int m = 0; m < 8; ++m)
#pragma unroll
        for (int n = 0; n < 4; ++n)
          acc[m][n] = __builtin_amdgcn_mfma_f32_16x16x32_bf16(af[m], bq[n], acc[m][n], 0, 0, 0);
      __builtin_amdgcn_s_setprio(0);
    }
  }

  __syncthreads();
#pragma unroll
  for (int m = 0; m < 8; ++m)
#pragma unroll
    for (int n = 0; n < 4; ++n)
#pragma unroll
      for (int j = 0; j < 4; ++j)
        smem.S[(wq << 6) + (n << 4) + fr][(wk << 7) + (m << 4) + (g << 2) + j] =
            f2h(acc[m][n][j]);
  __syncthreads();
#pragma unroll 1
  for (int it = 0; it < 16; ++it) {
    int cid = it * 512 + tid;
    int row = cid >> 5;
    int col = (cid & 31) << 3;
    s16x8 vv = *(const s16x8*)&smem.S[row][col];
    *(s16x8*)(sims + (size_t)(qloc0 + row) * M_N + kbase + col) = vv;
  }
  // per-row tile max from the stored f16 values (S stable since last barrier)
  if (tid < 256) {
    float mx = -1e38f;
#pragma unroll 1
    for (int k8 = 0; k8 < 32; ++k8) {
      s16x8 vv = *(const s16x8*)&smem.S[tid][k8 << 3];
#pragma unroll
      for (int e = 0; e < 8; ++e) mx = fmaxf(mx, h2f((unsigned short)vv[e]));
    }
    qmax[(size_t)(qloc0 + tid) * NTILES + keyTile] = mx;
  }
}

// ---------------- SCAN2: exact funnel top-16 per query row ------------------
// One wave per row. (1) 16 wave-extractions over 256 tile-maxes -> T.
// Exact: v < T implies >=16 actual values above v. (2) visit only tiles with
// max >= T, push values >= T (LDS atomic). (3) 16 exact (val, idx) wave
// extractions -> cand_idx.
__global__ __launch_bounds__(256) void scan2_kernel(const unsigned short* __restrict__ sims,
                                                    const float* __restrict__ qmax,
                                                    int* __restrict__ cand_idx,
                                                    int qchunk) {
  __shared__ float bufv[4][CAP];
  __shared__ int bufi[4][CAP];
  __shared__ int tlist[4][NTILES];
  __shared__ int cnts[4];
  __shared__ int tcnts[4];

  const int tid = threadIdx.x;
  const int lane = tid & 63;
  const int wv = tid >> 6;
  const int q = blockIdx.x * 4 + wv;            // row within chunk
  const int qg = qchunk * CHUNKQ + q;
  const unsigned short* row = sims + (size_t)q * M_N;

  if (lane == 0) { cnts[wv] = 0; tcnts[wv] = 0; }
  __syncthreads();   // uniform point

  // (1) load 4 tile-maxes per lane, 16 extractions -> T
  float4 m4 = *reinterpret_cast<const float4*>(qmax + (size_t)q * NTILES + (lane << 2));
  float tv[4] = {m4.x, m4.y, m4.z, m4.w};
  float keep[4] = {m4.x, m4.y, m4.z, m4.w};
  float T = -1e38f;
#pragma unroll 1
  for (int j = 0; j < 16; ++j) {
    float bv = tv[0]; int bi = (lane << 2);
#pragma unroll
    for (int s = 1; s < 4; ++s)
      if (better(tv[s], (lane << 2) + s, bv, bi)) { bv = tv[s]; bi = (lane << 2) + s; }
#pragma unroll
    for (int off = 32; off > 0; off >>= 1) {
      float ov = __shfl_xor(bv, off);
      int oi = __shfl_xor(bi, off);
      if (better(ov, oi, bv, bi)) { bv = ov; bi = oi; }
    }
    T = bv;
#pragma unroll
    for (int s = 0; s < 4; ++s)
      if ((lane << 2) + s == bi) tv[s] = -1e38f;
  }

  // (2a) build passing-tile list
#pragma unroll
  for (int s = 0; s < 4; ++s) {
    if (keep[s] >= T) {
      int p = atomicAdd(&tcnts[wv], 1);
      tlist[wv][p] = (lane << 2) + s;
    }
  }
  int tc = tcnts[wv];   // same-wave LDS ops complete in order

  // (2b) collect candidate values >= T from passing tiles
#pragma unroll 1
  for (int i = 0; i < tc; ++i) {
    int t = tlist[wv][i];
    ushort4 pk = *reinterpret_cast<const ushort4*>(row + t * GBM + (lane << 2));
    unsigned short pe[4] = {pk.x, pk.y, pk.z, pk.w};
#pragma unroll
    for (int e = 0; e < 4; ++e) {
      float v = h2f(pe[e]);
      if (v >= T) {
        int p = atomicAdd(&cnts[wv], 1);
        if (p < CAP) { bufv[wv][p] = v; bufi[wv][p] = t * GBM + (lane << 2) + e; }
      }
    }
  }
  int n = cnts[wv];
  if (n > CAP) n = CAP;

  // (3) exact top-16 extraction from buffer
  float cv[CAP / 64];
  int ci[CAP / 64];
#pragma unroll
  for (int s = 0; s < CAP / 64; ++s) {
    int id = s * 64 + lane;
    bool ok = id < n;
    cv[s] = ok ? bufv[wv][id] : -1e38f;
    ci[s] = ok ? bufi[wv][id] : 0;
  }
#pragma unroll 1
  for (int j = 0; j < 16; ++j) {
    float bv = cv[0]; int bi = ci[0];
#pragma unroll
    for (int s = 1; s < CAP / 64; ++s)
      if (better(cv[s], ci[s], bv, bi)) { bv = cv[s]; bi = ci[s]; }
#pragma unroll
    for (int off = 32; off > 0; off >>= 1) {
      float ov = __shfl_xor(bv, off);
      int oi = __shfl_xor(bi, off);
      if (better(ov, oi, bv, bi)) { bv = ov; bi = oi; }
    }
    if (lane == 0) cand_idx[(size_t)qg * 16 + j] = bi;
#pragma unroll
    for (int s = 0; s < CAP / 64; ++s)
      if (ci[s] == bi) cv[s] = -1e38f;
  }
}

// ---------------- RESCORE: exact fp32 rescore of 16 + select + gather -------
__global__ __launch_bounds__(256) void rescore_kernel(const float* __restrict__ qn,
                                                      const float* __restrict__ keys,
                                                      const float* __restrict__ values,
                                                      const float* __restrict__ rnk,
                                                      const int* __restrict__ cand_idx,
                                                      float* __restrict__ out) {
  const int q = blockIdx.x;
  const int tid = threadIdx.x;
  const int lane = tid & 63;
  const int w = tid >> 6;
  __shared__ int si[16];
  __shared__ float rsc[16];
  if (tid < 16) si[tid] = cand_idx[(size_t)q * 16 + tid];
  __syncthreads();
  const float* qrow = &qn[(size_t)q * D_N + lane * 16];
  float4 qv0 = *reinterpret_cast<const float4*>(qrow + 0);
  float4 qv1 = *reinterpret_cast<const float4*>(qrow + 4);
  float4 qv2 = *reinterpret_cast<const float4*>(qrow + 8);
  float4 qv3 = *reinterpret_cast<const float4*>(qrow + 12);
  for (int c = w; c < 16; c += 4) {
    int id = si[c];
    const float* kr = &keys[(size_t)id * D_N + lane * 16];
    float4 k0 = *reinterpret_cast<const float4*>(kr + 0);
    float4 k1 = *reinterpret_cast<const float4*>(kr + 4);
    float4 k2 = *reinterpret_cast<const float4*>(kr + 8);
    float4 k3 = *reinterpret_cast<const float4*>(kr + 12);
    float s = qv0.x * k0.x + qv0.y * k0.y + qv0.z * k0.z + qv0.w * k0.w
            + qv1.x * k1.x + qv1.y * k1.y + qv1.z * k1.z + qv1.w * k1.w
            + qv2.x * k2.x + qv2.y * k2.y + qv2.z * k2.z + qv2.w * k2.w
            + qv3.x * k3.x + qv3.y * k3.y + qv3.z * k3.z + qv3.w * k3.w;
#pragma unroll
    for (int off = 32; off > 0; off >>= 1) s += __shfl_down(s, off);
    if (lane == 0) rsc[c] = s * rnk[id];
  }
  __syncthreads();
  __shared__ int sel[TOPK];
  if (tid == 0) {
    unsigned used = 0;
    for (int j = 0; j < TOPK; ++j) {
      int best = -1;
      for (int c = 0; c < 16; ++c) {
        if ((used >> c) & 1u) continue;
        if (best < 0 || better(rsc[c], si[c], rsc[best], si[best])) best = c;
      }
      used |= 1u << best;
      sel[j] = si[best];
    }
  }
  __syncthreads();
#pragma unroll
  for (int j = 0; j < TOPK; ++j) {
    int rowi = sel[j];
    float4 v = *reinterpret_cast<const float4*>(&values[(size_t)rowi * D_N + tid * 4]);
    *reinterpret_cast<float4*>(&out[(size_t)q * (TOPK * D_N) + j * D_N + tid * 4]) = v;
  }
}

// =================== FALLBACK (R16, validated) ==============================
__global__ __launch_bounds__(256, 3) void simsb_kernel(const unsigned short* __restrict__ qb,
                                                       const unsigned short* __restrict__ kb,
                                                       float* __restrict__ cand_val,
                                                       int* __restrict__ cand_idx) {
  __shared__ __align__(16) union SmemU {
    struct {
      unsigned short A[3][BM * BK];
      unsigned short B[3][BN * BK];
    } ab;
    struct {
      float v[BM * 4 * TOPK];
      int i[BM * 4 * TOPK];
    } mg;
  } smem;

  const int tid = threadIdx.x;
  const int lane = tid & 63;
  const int wid = tid >> 6;

  const int orig = blockIdx.x;
  const int x = orig & 7;
  const int idx = orig >> 3;
  const int qtile = ((x >> 1) << 3) + (idx & 7);
  const int seg = ((x & 1) << 4) + (idx >> 3);
  const int qbase = qtile * BM;
  const int segBase = seg * KPS;

  const int srow = (wid << 5) + (lane >> 2);
  const int scol = (((lane & 3) ^ ((lane >> 3) & 3)) << 3);
  const unsigned short* aSeg = qb + (size_t)(qbase + srow) * D_N + scol;
  const unsigned short* bSeg = kb + (size_t)(segBase + srow) * D_N + scol;

  const int fr = lane & 15;
  const int g = lane >> 4;
  const int chunk_phys = g ^ ((fr >> 1) & 3);
  const unsigned short* rB = &smem.ab.B[0][0] + (fr << 5) + (chunk_phys << 3);
  const unsigned short* rA = &smem.ab.A[0][0] + (((wid << 5) + fr) << 5) + (chunk_phys << 3);

  float lv[2][TOPK];
  int li[2][TOPK];
#pragma unroll
  for (int n = 0; n < 2; ++n)
#pragma unroll
    for (int j = 0; j < TOPK; ++j) { lv[n][j] = -1e30f; li[n][j] = 0x7fffffff; }

  f32x4 acc[8][2];
#pragma unroll
  for (int m = 0; m < 8; ++m)
#pragma unroll
    for (int n = 0; n < 2; ++n) acc[m][n] = (f32x4)0.0f;

#pragma unroll
  for (int p = 0; p < 2; ++p) {
    const unsigned short* aS = aSeg + (p << 5);
    const unsigned short* bS = bSeg + (p << 5);
    unsigned short* Ad = &smem.ab.A[p][0] + (wid << 10);
    unsigned short* Bd = &smem.ab.B[p][0] + (wid << 10);
    gll16(Ad, aS);
    gll16(Ad + 512, aS + (size_t)16 * D_N);
    gll16(Bd, bS);
    gll16(Bd + 512, bS + (size_t)16 * D_N);
  }

  const unsigned short* aP0 = aSeg + 64;
  const unsigned short* aP1 = aP0 + (size_t)16 * D_N;
  const unsigned short* bP0 = bSeg + 64;
  const unsigned short* bP1 = bP0 + (size_t)16 * D_N;

#define SWAIT_(N) asm volatile("s_waitcnt vmcnt(" #N ")" ::: "memory")
#define SWAIT(N) SWAIT_(N)

#define FOLD(V)                                                               \
  {                                                                           \
    const int kb0 = segBase + (((V) >> 5) << 7) + (g << 2);                   \
    _Pragma("unroll")                                                         \
    for (int n = 0; n < 2; ++n)                                               \
      _Pragma("unroll")                                                       \
      for (int m = 0; m < 8; ++m) {                                           \
        float q0 = acc[m][n][0], q1 = acc[m][n][1];                           \
        float q2 = acc[m][n][2], q3 = acc[m][n][3];                           \
        acc[m][n] = (f32x4)0.0f;                                              \
        float mx = fmaxf(fmaxf(q0, q1), fmaxf(q2, q3));                       \
        const int id0 = kb0 + (m << 4);                                       \
        if (better(mx, id0, lv[n][TOPK - 1], li[n][TOPK - 1])) {              \
          float vals[4] = {q0, q1, q2, q3};                                   \
          _Pragma("unroll")                                                   \
          for (int j = 0; j < 4; ++j) {                                       \
            float val = vals[j];                                              \
            int id = id0 + j;                                                 \
            if (better(val, id, lv[n][TOPK - 1], li[n][TOPK - 1])) {          \
              float cv = val; int ci = id;                                    \
              _Pragma("unroll")                                               \
              for (int p = 0; p < TOPK; ++p) {                                \
                if (better(cv, ci, lv[n][p], li[n][p])) {                     \
                  float tv = lv[n][p]; int ti = li[n][p];                     \
                  lv[n][p] = cv; li[n][p] = ci;                               \
                  cv = tv; ci = ti;                                           \
                }                                                             \
              }                                                               \
            }                                                                 \
          }                                                                   \
        }                                                                     \
      }                                                                       \
  }

#define STEP(V, SLOT, WAITN, RESTAGE)                                         \
  {                                                                           \
    SWAIT(WAITN);                                                             \
    __builtin_amdgcn_sched_barrier(0);                                        \
    __builtin_amdgcn_s_barrier();                                             \
    __builtin_amdgcn_sched_barrier(0);                                        \
    if (RESTAGE) {                                                            \
      unsigned short* Ad = &smem.ab.A[((SLOT) + 2) % 3][0] + (wid << 10);     \
      unsigned short* Bd = &smem.ab.B[((SLOT) + 2) % 3][0] + (wid << 10);     \
      gll16(Ad, aP0);                                                         \
      gll16(Ad + 512, aP1);                                                   \
      gll16(Bd, bP0);                                                         \
      gll16(Bd + 512, bP1);                                                   \
    }                                                                         \
    {                                                                         \
      const bool wrp = (((V) & 31) == 29);                                    \
      const int dA = wrp ? -992 : 32;                                         \
      const int dB = wrp ? 130080 : 32;                                       \
      aP0 += dA; aP1 += dA; bP0 += dB; bP1 += dB;                             \
    }                                                                         \
    s16x8 af[8], bq[2];                                                       \
    _Pragma("unroll")                                                         \
    for (int m = 0; m < 8; ++m)                                               \
      af[m] = *(const s16x8*)(rB + (SLOT) * 4096 + (m << 9));                 \
    bq[0] = *(const s16x8*)(rA + (SLOT) * 4096);                              \
    bq[1] = *(const s16x8*)(rA + (SLOT) * 4096 + 512);                        \
    __builtin_amdgcn_s_setprio(1);                                            \
    _Pragma("unroll")                                                         \
    for (int m = 0; m < 8; ++m) {                                             \
      acc[m][0] = __builtin_amdgcn_mfma_f32_16x16x32_bf16(af[m], bq[0], acc[m][0], 0, 0, 0); \
      acc[m][1] = __builtin_amdgcn_mfma_f32_16x16x32_bf16(af[m], bq[1], acc[m][1], 0, 0, 0); \
    }                                                                         \
    __builtin_amdgcn_s_setprio(0);                                            \
    if (((V) & 31) == 31) FOLD(V)                                             \
  }

#pragma unroll 1
  for (int vb = 0; vb < NSTEP - 2; vb += 3) {
    STEP(vb + 0, 0, 4, 1)
    STEP(vb + 1, 1, 4, 1)
    STEP(vb + 2, 2, 4, 1)
  }
  STEP(510, 0, 4, 0)
  STEP(511, 1, 0, 0)
#undef STEP
#undef FOLD
#undef SWAIT
#undef SWAIT_

  __syncthreads();

#pragma unroll
  for (int n = 0; n < 2; ++n) {
    const int ql = (wid << 5) + (n << 4) + fr;
#pragma unroll
    for (int j = 0; j < TOPK; ++j) {
      smem.mg.v[((ql << 2) + g) * TOPK + j] = lv[n][j];
      smem.mg.i[((ql << 2) + g) * TOPK + j] = li[n][j];
    }
  }
  __syncthreads();

  if (tid < BM) {
    const int rb = tid << 5;
    int p0 = 0, p1 = 0, p2 = 0, p3 = 0;
    size_t base = (size_t)(qbase + tid) * CANDS + seg * TOPK;
#pragma unroll
    for (int j = 0; j < TOPK; ++j) {
      float v0 = smem.mg.v[rb + 0 + p0];  int i0 = smem.mg.i[rb + 0 + p0];
      float v1 = smem.mg.v[rb + 8 + p1];  int i1 = smem.mg.i[rb + 8 + p1];
      float v2 = smem.mg.v[rb + 16 + p2]; int i2 = smem.mg.i[rb + 16 + p2];
      float v3 = smem.mg.v[rb + 24 + p3]; int i3 = smem.mg.i[rb + 24 + p3];
      float bv = v0; int bi = i0; int sel = 0;
      if (better(v1, i1, bv, bi)) { bv = v1; bi = i1; sel = 1; }
      if (better(v2, i2, bv, bi)) { bv = v2; bi = i2; sel = 2; }
      if (better(v3, i3, bv, bi)) { bv = v3; bi = i3; sel = 3; }
      cand_val[base + j] = bv;
      cand_idx[base + j] = bi;
      p0 += (sel == 0); p1 += (sel == 1); p2 += (sel == 2); p3 += (sel == 3);
    }
  }
}

__global__ __launch_bounds__(256) void merge_kernel(const float* __restrict__ qn,
                                                    const float* __restrict__ keys,
                                                    const float* __restrict__ values,
                                                    const float* __restrict__ rnk,
                                                    const float* __restrict__ cand_val,
                                                    const int* __restrict__ cand_idx,
                                                    float* __restrict__ out) {
  const int q = blockIdx.x;
  const int tid = threadIdx.x;
  const int lane = tid & 63;
  const int w = tid >> 6;
  __shared__ float sv[CANDS];
  __shared__ int si[CANDS];
  sv[tid] = cand_val[(size_t)q * CANDS + tid];
  si[tid] = cand_idx[(size_t)q * CANDS + tid];
  __syncthreads();
  for (int k = 2; k <= CANDS; k <<= 1) {
    for (int j = k >> 1; j > 0; j >>= 1) {
      int ixj = tid ^ j;
      if (ixj > tid) {
        float v0 = sv[tid], v1 = sv[ixj];
        int i0 = si[tid], i1 = si[ixj];
        bool desc = ((tid & k) == 0);
        bool dosw = desc ? better(v1, i1, v0, i0) : better(v0, i0, v1, i1);
        if (dosw) { sv[tid] = v1; si[tid] = i1; sv[ixj] = v0; si[ixj] = i0; }
      }
      __syncthreads();
    }
  }
  __shared__ float rsc[NRES];
  const float* qrow = &qn[(size_t)q * D_N + lane * 16];
  float4 qv0 = *reinterpret_cast<const float4*>(qrow + 0);
  float4 qv1 = *reinterpret_cast<const float4*>(qrow + 4);
  float4 qv2 = *reinterpret_cast<const float4*>(qrow + 8);
  float4 qv3 = *reinterpret_cast<const float4*>(qrow + 12);
  for (int c = w; c < NRES; c += 4) {
    int id = si[c];
    const float* kr = &keys[(size_t)id * D_N + lane * 16];
    float4 k0 = *reinterpret_cast<const float4*>(kr + 0);
    float4 k1 = *reinterpret_cast<const float4*>(kr + 4);
    float4 k2 = *reinterpret_cast<const float4*>(kr + 8);
    float4 k3 = *reinterpret_cast<const float4*>(kr + 12);
    float s = qv0.x * k0.x + qv0.y * k0.y + qv0.z * k0.z + qv0.w * k0.w
            + qv1.x * k1.x + qv1.y * k1.y + qv1.z * k1.z + qv1.w * k1.w
            + qv2.x * k2.x + qv2.y * k2.y + qv2.z * k2.z + qv2.w * k2.w
            + qv3.x * k3.x + qv3.y * k3.y + qv3.z * k3.z + qv3.w * k3.w;
#pragma unroll
    for (int off = 32; off > 0; off >>= 1) s += __shfl_down(s, off);
    if (lane == 0) rsc[c] = s * rnk[id];
  }
  __syncthreads();
  __shared__ int sel[TOPK];
  if (tid == 0) {
    unsigned used = 0;
    for (int j = 0; j < TOPK; ++j) {
      int best = -1;
      for (int c = 0; c < NRES; ++c) {
        if ((used >> c) & 1u) continue;
        if (best < 0 || better(rsc[c], si[c], rsc[best], si[best])) best = c;
      }
      used |= 1u << best;
      sel[j] = si[best];
    }
  }
  __syncthreads();
#pragma unroll
  for (int j = 0; j < TOPK; ++j) {
    int row = sel[j];
    float4 v = *reinterpret_cast<const float4*>(&values[(size_t)row * D_N + tid * 4]);
    *reinterpret_cast<float4*>(&out[(size_t)q * (TOPK * D_N) + j * D_N + tid * 4]) = v;
  }
}

extern "C" void kernel_launch(void* const* d_in, const int* in_sizes, int n_in,
                              void* d_out, int out_size, void* d_ws, size_t ws_size,
                              hipStream_t stream) {
  const float* query  = (const float*)d_in[0];
  const float* keys   = (const float*)d_in[1];
  const float* values = (const float*)d_in[2];
  float* out = (float*)d_out;
  char* ws = (char*)d_ws;

  const size_t offQn   = 0;
  const size_t offQb   = offQn + (size_t)Q_N * D_N * 4;
  const size_t offKb   = offQb + (size_t)Q_N * D_N * 2;
  const size_t offRnk  = offKb + (size_t)M_N * D_N * 2;
  const size_t offCv   = offRnk + (size_t)M_N * 4;
  const size_t offCi   = offCv + (size_t)Q_N * CANDS * 4;
  const size_t offSims = offCi + (size_t)Q_N * CANDS * 4;
  const size_t offQmax = offSims + (size_t)CHUNKQ * M_N * 2;
  const size_t needPrimary = offQmax + (size_t)CHUNKQ * NTILES * 4;

  float* qn = (float*)(ws + offQn);
  unsigned short* qb = (unsigned short*)(ws + offQb);
  unsigned short* kb = (unsigned short*)(ws + offKb);
  float* rnk = (float*)(ws + offRnk);
  float* cand_val = (float*)(ws + offCv);
  int* cand_idx = (int*)(ws + offCi);
  unsigned short* sims = (unsigned short*)(ws + offSims);
  float* qmax = (float*)(ws + offQmax);

  hipLaunchKernelGGL(knorm_scale_kernel, dim3(M_N), dim3(256), 0, stream, keys, kb, rnk);
  hipLaunchKernelGGL(qnorm_dual_kernel, dim3(Q_N), dim3(256), 0, stream, query, qn, qb);

  if (ws_size >= needPrimary) {
    for (int c = 0; c < NCHUNK; ++c) {
      hipLaunchKernelGGL(gemm_kernel, dim3(256 * 4), dim3(512), 0, stream,
                         qb, kb, sims, qmax, c);
      hipLaunchKernelGGL(scan2_kernel, dim3(CHUNKQ / 4), dim3(256), 0, stream,
                         sims, qmax, cand_idx, c);
    }
    hipLaunchKernelGGL(rescore_kernel, dim3(Q_N), dim3(256), 0, stream,
                       qn, keys, values, rnk, cand_idx, out);
  } else {
    hipLaunchKernelGGL(simsb_kernel, dim3(QT128 * SEGS), dim3(256), 0, stream,
                       qb, kb, cand_val, cand_idx);
    hipLaunchKernelGGL(merge_kernel, dim3(Q_N), dim3(256), 0, stream,
                       qn, keys, values, rnk, cand_val, cand_idx, out);
  }
}